// Round 4
// baseline (355.711 us; speedup 1.0000x reference)
//
#include <hip/hip_runtime.h>
#include <hip/hip_bf16.h>

typedef __attribute__((ext_vector_type(8))) short bf16x8;
typedef __attribute__((ext_vector_type(4))) float f32x4;
typedef __attribute__((ext_vector_type(4))) unsigned short us4;

__device__ __forceinline__ unsigned short f2bf(float f) {
    unsigned int u = __builtin_bit_cast(unsigned int, f);
    unsigned int r = (u + 0x7FFFu + ((u >> 16) & 1u)) >> 16;
    return (unsigned short)r;
}
__device__ __forceinline__ float bf2f(unsigned short h) {
    unsigned int u = ((unsigned int)h) << 16;
    return __builtin_bit_cast(float, u);
}

__device__ __forceinline__ void gload_lds16(const void* g, void* l) {
    __builtin_amdgcn_global_load_lds(
        (const __attribute__((address_space(1))) unsigned int*)g,
        (__attribute__((address_space(3))) unsigned int*)l, 16, 0, 0);
}

// ---------------------------------------------------------------------------
// KV projection. Output layout (bf16): KV2[row][h*128 + (isV?64:0) + d],
// i.e. per (row, head) one contiguous 256B chunk [K 64 dims | V 64 dims].
// Grid 1024 = 512 M-groups x 2 col-halves (half 0 -> all K cols, half 1 -> V).
// Block: 512 threads, 8 waves; wave owns 32 output cols, W held in 64 VGPRs.
// A staged 32 rows/tile, double-buffered, 8 tiles (256 rows) per block.
// Swapped-operand MFMA: lane holds 4 consecutive cols -> 8B us4 stores.
// ---------------------------------------------------------------------------
__global__ __launch_bounds__(512, 4) void kv_gemm_rb(
    const float* __restrict__ A,
    const float* __restrict__ Wk, const float* __restrict__ bk,
    const float* __restrict__ Wv, const float* __restrict__ bv,
    unsigned short* __restrict__ KV2)
{
    __shared__ unsigned short Abuf[2][32 * 256];   // 2 x 16 KB, swizzled bf16

    const int tid = threadIdx.x;
    const int wave = tid >> 6, lane = tid & 63;

    // chunked remap so (colhalf 0/1) of one M-group land on the same XCD
    const int g = (blockIdx.x & 7) * 128 + (blockIdx.x >> 3);   // 1024 = 8*128
    const int colhalf = g & 1;
    const size_t mb = (size_t)(g >> 1) * 256;
    const int colbase = colhalf * 256 + wave * 32;

    // ---- W fragments to registers (once) ----
    bf16x8 bfrag[2][8];
    float biasr[2][4];
    int inner0[2];
    #pragma unroll
    for (int ni = 0; ni < 2; ++ni) {
        int jcol = colbase + ni * 16 + (lane & 15);
        const float* Wr = (jcol < 256) ? (Wk + (size_t)jcol * 256)
                                       : (Wv + (size_t)(jcol - 256) * 256);
        #pragma unroll
        for (int ks = 0; ks < 8; ++ks) {
            int k0 = ks * 32 + ((lane >> 4) << 3);
            float4 x = *(const float4*)(Wr + k0);
            float4 y = *(const float4*)(Wr + k0 + 4);
            bf16x8 f;
            f[0] = (short)f2bf(x.x); f[1] = (short)f2bf(x.y);
            f[2] = (short)f2bf(x.z); f[3] = (short)f2bf(x.w);
            f[4] = (short)f2bf(y.x); f[5] = (short)f2bf(y.y);
            f[6] = (short)f2bf(y.z); f[7] = (short)f2bf(y.w);
            bfrag[ni][ks] = f;
        }
        int j0 = colbase + ni * 16 + ((lane >> 4) << 2);
        const float* bsrc = (j0 < 256) ? (bk + j0) : (bv + j0 - 256);
        float4 bb = *(const float4*)bsrc;
        biasr[ni][0] = bb.x; biasr[ni][1] = bb.y; biasr[ni][2] = bb.z; biasr[ni][3] = bb.w;
        if (j0 < 256) inner0[ni] = (j0 >> 6) * 128 + (j0 & 63);
        else { int t2 = j0 - 256; inner0[ni] = (t2 >> 6) * 128 + 64 + (t2 & 63); }
    }

    const int srow = tid >> 4, sseg = tid & 15;   // staging role
    const int sbyte0 = srow * 512 + sseg * 32;
    const int ssw = (srow & 7) << 4;

    // prologue: stage tile 0
    {
        const float* src = A + (mb + srow) * 256 + sseg * 16;
        float4 a0 = *(const float4*)(src + 0);
        float4 a1 = *(const float4*)(src + 4);
        float4 a2 = *(const float4*)(src + 8);
        float4 a3 = *(const float4*)(src + 12);
        us4 h0, h1, h2, h3;
        h0.x=f2bf(a0.x); h0.y=f2bf(a0.y); h0.z=f2bf(a0.z); h0.w=f2bf(a0.w);
        h1.x=f2bf(a1.x); h1.y=f2bf(a1.y); h1.z=f2bf(a1.z); h1.w=f2bf(a1.w);
        h2.x=f2bf(a2.x); h2.y=f2bf(a2.y); h2.z=f2bf(a2.z); h2.w=f2bf(a2.w);
        h3.x=f2bf(a3.x); h3.y=f2bf(a3.y); h3.z=f2bf(a3.z); h3.w=f2bf(a3.w);
        char* dst = (char*)Abuf[0];
        *(us4*)(dst + ((sbyte0 +  0) ^ ssw)) = h0;
        *(us4*)(dst + ((sbyte0 +  8) ^ ssw)) = h1;
        *(us4*)(dst + ((sbyte0 + 16) ^ ssw)) = h2;
        *(us4*)(dst + ((sbyte0 + 24) ^ ssw)) = h3;
    }
    __syncthreads();

    for (int t = 0; t < 8; ++t) {
        const bool pf = (t + 1) < 8;
        float4 a0, a1, a2, a3;
        if (pf) {   // issue next-tile loads early (hide HBM under MFMA)
            const float* src = A + (mb + (t + 1) * 32 + srow) * 256 + sseg * 16;
            a0 = *(const float4*)(src + 0);
            a1 = *(const float4*)(src + 4);
            a2 = *(const float4*)(src + 8);
            a3 = *(const float4*)(src + 12);
        }

        f32x4 acc[2][2] = {};
        const char* Ab = (const char*)Abuf[t & 1];
        #pragma unroll
        for (int ks = 0; ks < 8; ++ks) {
            bf16x8 af[2];
            #pragma unroll
            for (int mi = 0; mi < 2; ++mi) {
                int row = mi * 16 + (lane & 15);
                int byte = row * 512 + ks * 64 + ((lane >> 4) << 4);
                af[mi] = *(const bf16x8*)(Ab + (byte ^ ((row & 7) << 4)));
            }
            #pragma unroll
            for (int ni = 0; ni < 2; ++ni)
                #pragma unroll
                for (int mi = 0; mi < 2; ++mi)
                    acc[mi][ni] = __builtin_amdgcn_mfma_f32_16x16x32_bf16(
                        bfrag[ni][ks], af[mi], acc[mi][ni], 0, 0, 0);
        }

        // epilogue: lane holds 4 consecutive cols for row m -> one us4 store
        #pragma unroll
        for (int ni = 0; ni < 2; ++ni) {
            #pragma unroll
            for (int mi = 0; mi < 2; ++mi) {
                size_t m = mb + (size_t)t * 32 + mi * 16 + (lane & 15);
                us4 h;
                #pragma unroll
                for (int r = 0; r < 4; ++r)
                    h[r] = f2bf(fmaxf(acc[mi][ni][r] + biasr[ni][r], 0.f));
                *(us4*)(KV2 + m * 512 + inner0[ni]) = h;
            }
        }

        if (pf) {
            us4 h0, h1, h2, h3;
            h0.x=f2bf(a0.x); h0.y=f2bf(a0.y); h0.z=f2bf(a0.z); h0.w=f2bf(a0.w);
            h1.x=f2bf(a1.x); h1.y=f2bf(a1.y); h1.z=f2bf(a1.z); h1.w=f2bf(a1.w);
            h2.x=f2bf(a2.x); h2.y=f2bf(a2.y); h2.z=f2bf(a2.z); h2.w=f2bf(a2.w);
            h3.x=f2bf(a3.x); h3.y=f2bf(a3.y); h3.z=f2bf(a3.z); h3.w=f2bf(a3.w);
            char* dst = (char*)Abuf[(t + 1) & 1];
            *(us4*)(dst + ((sbyte0 +  0) ^ ssw)) = h0;
            *(us4*)(dst + ((sbyte0 +  8) ^ ssw)) = h1;
            *(us4*)(dst + ((sbyte0 + 16) ^ ssw)) = h2;
            *(us4*)(dst + ((sbyte0 + 24) ^ ssw)) = h3;
        }
        __syncthreads();
    }
}

// ---------------------------------------------------------------------------
// Small GEMM (M=4096, N=256, K=256), single K-tile, one barrier.
// BM=BN=64; 4 waves, wave owns 16 rows x 64 cols. Swapped-operand MFMA ->
// float4 stores. out = act(A @ W^T + b) * scale, fp32.
// ---------------------------------------------------------------------------
template<int RELU>
__global__ __launch_bounds__(256) void gemm_proj(
    const float* __restrict__ A, const float* __restrict__ W,
    const float* __restrict__ bias, float* __restrict__ out, float scale)
{
    __shared__ unsigned short As[64 * 256];
    __shared__ unsigned short Bs[64 * 256];
    char* AsB = (char*)As;
    char* BsB = (char*)Bs;

    const int tid = threadIdx.x;
    const int wave = tid >> 6, lane = tid & 63;
    const int m0 = blockIdx.x * 64;
    const int jbase = blockIdx.y * 64;

    #pragma unroll
    for (int i = 0; i < 4; ++i) {
        int f = tid + i * 256;
        int row = f >> 4, seg = f & 15;
        int byte0 = row * 512 + seg * 32;
        int sw = (row & 7) << 4;
        {
            const float* pa = A + (size_t)(m0 + row) * 256 + seg * 16;
            float4 a0 = *(const float4*)(pa + 0);
            float4 a1 = *(const float4*)(pa + 4);
            float4 a2 = *(const float4*)(pa + 8);
            float4 a3 = *(const float4*)(pa + 12);
            us4 h0, h1, h2, h3;
            h0.x=f2bf(a0.x); h0.y=f2bf(a0.y); h0.z=f2bf(a0.z); h0.w=f2bf(a0.w);
            h1.x=f2bf(a1.x); h1.y=f2bf(a1.y); h1.z=f2bf(a1.z); h1.w=f2bf(a1.w);
            h2.x=f2bf(a2.x); h2.y=f2bf(a2.y); h2.z=f2bf(a2.z); h2.w=f2bf(a2.w);
            h3.x=f2bf(a3.x); h3.y=f2bf(a3.y); h3.z=f2bf(a3.z); h3.w=f2bf(a3.w);
            *(us4*)(AsB + ((byte0 +  0) ^ sw)) = h0;
            *(us4*)(AsB + ((byte0 +  8) ^ sw)) = h1;
            *(us4*)(AsB + ((byte0 + 16) ^ sw)) = h2;
            *(us4*)(AsB + ((byte0 + 24) ^ sw)) = h3;
        }
        {
            const float* pw = W + (size_t)(jbase + row) * 256 + seg * 16;
            float4 a0 = *(const float4*)(pw + 0);
            float4 a1 = *(const float4*)(pw + 4);
            float4 a2 = *(const float4*)(pw + 8);
            float4 a3 = *(const float4*)(pw + 12);
            us4 h0, h1, h2, h3;
            h0.x=f2bf(a0.x); h0.y=f2bf(a0.y); h0.z=f2bf(a0.z); h0.w=f2bf(a0.w);
            h1.x=f2bf(a1.x); h1.y=f2bf(a1.y); h1.z=f2bf(a1.z); h1.w=f2bf(a1.w);
            h2.x=f2bf(a2.x); h2.y=f2bf(a2.y); h2.z=f2bf(a2.z); h2.w=f2bf(a2.w);
            h3.x=f2bf(a3.x); h3.y=f2bf(a3.y); h3.z=f2bf(a3.z); h3.w=f2bf(a3.w);
            *(us4*)(BsB + ((byte0 +  0) ^ sw)) = h0;
            *(us4*)(BsB + ((byte0 +  8) ^ sw)) = h1;
            *(us4*)(BsB + ((byte0 + 16) ^ sw)) = h2;
            *(us4*)(BsB + ((byte0 + 24) ^ sw)) = h3;
        }
    }
    __syncthreads();

    f32x4 acc[4] = {};
    #pragma unroll
    for (int ks = 0; ks < 8; ++ks) {
        int arow = wave * 16 + (lane & 15);
        int abyte = arow * 512 + ks * 64 + ((lane >> 4) << 4);
        bf16x8 af = *(const bf16x8*)(AsB + (abyte ^ ((arow & 7) << 4)));
        #pragma unroll
        for (int ni = 0; ni < 4; ++ni) {
            int brow = ni * 16 + (lane & 15);
            int bbyte = brow * 512 + ks * 64 + ((lane >> 4) << 4);
            bf16x8 bfr = *(const bf16x8*)(BsB + (bbyte ^ ((brow & 7) << 4)));
            acc[ni] = __builtin_amdgcn_mfma_f32_16x16x32_bf16(bfr, af, acc[ni], 0, 0, 0);
        }
    }

    int m = m0 + wave * 16 + (lane & 15);
    #pragma unroll
    for (int ni = 0; ni < 4; ++ni) {
        int j0 = jbase + ni * 16 + ((lane >> 4) << 2);
        float4 bb = *(const float4*)(bias + j0);
        float4 o;
        o.x = acc[ni][0] + bb.x; o.y = acc[ni][1] + bb.y;
        o.z = acc[ni][2] + bb.z; o.w = acc[ni][3] + bb.w;
        if (RELU) {
            o.x = fmaxf(o.x, 0.f); o.y = fmaxf(o.y, 0.f);
            o.z = fmaxf(o.z, 0.f); o.w = fmaxf(o.w, 0.f);
        }
        o.x *= scale; o.y *= scale; o.z *= scale; o.w *= scale;
        *(float4*)(out + (size_t)m * 256 + j0) = o;
    }
}

// ---------------------------------------------------------------------------
// Attention: one 64-thread block per (sample, head). Stage ceil(len/4)*4 rows
// of the 256B [K|V] chunk to LDS (pre-swizzled source), lane-per-neighbor
// scores, butterfly softmax, split-half PV.
// ---------------------------------------------------------------------------
__global__ __launch_bounds__(64) void attn_kernel(
    const float* __restrict__ Q, const unsigned short* __restrict__ KV2,
    const int* __restrict__ starts, const int* __restrict__ ends,
    float* __restrict__ out)
{
    __shared__ unsigned short kvs[64 * 128];   // 16 KB: row r at bytes [r*256, r*256+256)
    __shared__ float qs[64];
    __shared__ float aw[64];

    const int bid = blockIdx.x;
    const int idx = ((bid & 7) << 11) | (bid >> 3);   // XCD-chunked (16384 = 8*2048)
    const int b = idx >> 2, h = idx & 3;
    const int ln = threadIdx.x;
    const int start = starts[b];
    const int len = ends[b] - start;   // 1..64

    // stage rows [0, ceil(len/4)*4): instr i covers 4 rows (1 KB)
    {
        const int r4 = ln >> 4, c = ln & 15;
        #pragma unroll
        for (int i = 0; i < 16; ++i) {
            if (i * 4 < len) {
                int rr = i * 4 + r4;
                const char* src = (const char*)(KV2 + (size_t)(start + rr) * 512 + h * 128)
                                  + ((c * 16) ^ ((rr & 7) << 4));
                gload_lds16(src, (char*)kvs + i * 1024 + ln * 16);
            }
        }
    }
    qs[ln] = Q[(size_t)b * 256 + h * 64 + ln];
    __syncthreads();

    // hoist q to registers
    float2 qreg[32];
    #pragma unroll
    for (int j = 0; j < 32; ++j)
        qreg[j] = *(const float2*)(qs + 2 * j);

    // score: lane = neighbor
    float sx = 0.f, sy = 0.f;
    {
        const char* krow = (const char*)kvs + ln * 256;
        const int sw = (ln & 7) << 4;
        #pragma unroll
        for (int j8 = 0; j8 < 8; ++j8) {
            bf16x8 kf = *(const bf16x8*)(krow + ((j8 * 16) ^ sw));
            #pragma unroll
            for (int p = 0; p < 4; ++p) {
                float2 q2 = qreg[j8 * 4 + p];
                sx = fmaf(q2.x, bf2f((unsigned short)kf[2 * p]), sx);
                sy = fmaf(q2.y, bf2f((unsigned short)kf[2 * p + 1]), sy);
            }
        }
    }
    float s = (ln < len) ? (sx + sy) : -3.0e38f;
    float mx = s;
    #pragma unroll
    for (int off = 32; off; off >>= 1) mx = fmaxf(mx, __shfl_xor(mx, off));
    float e = (ln < len) ? __expf(s - mx) : 0.f;
    float sum = e;
    #pragma unroll
    for (int off = 32; off; off >>= 1) sum += __shfl_xor(sum, off);
    aw[ln] = e / sum;
    __syncthreads();

    // PV: half 0 -> m in [0,32), half 1 -> [32,64); lane covers dims 2dl, 2dl+1
    const int half = ln >> 5, dl = ln & 31;
    int nm = len - half * 32; nm = nm < 0 ? 0 : (nm > 32 ? 32 : nm);
    float a0 = 0.f, a1 = 0.f;
    const char* vb = (const char*)kvs + half * 32 * 256;
    const int voff = 128 + dl * 4;
    for (int mm = 0; mm < nm; ++mm) {
        unsigned int vv = *(const unsigned int*)(vb + mm * 256 + (voff ^ ((mm & 7) << 4)));
        float awm = aw[half * 32 + mm];
        a0 = fmaf(awm, __builtin_bit_cast(float, vv << 16), a0);
        a1 = fmaf(awm, __builtin_bit_cast(float, vv & 0xFFFF0000u), a1);
    }
    a0 += __shfl_xor(a0, 32);
    a1 += __shfl_xor(a1, 32);
    if (ln < 32) {
        float2 o; o.x = a0; o.y = a1;
        *(float2*)(out + (size_t)b * 256 + h * 64 + 2 * dl) = o;
    }
}

extern "C" void kernel_launch(void* const* d_in, const int* in_sizes, int n_in,
                              void* d_out, int out_size, void* d_ws, size_t ws_size,
                              hipStream_t stream) {
    const float* enc    = (const float*)d_in[0];
    const float* social = (const float*)d_in[1];
    const float* Wq = (const float*)d_in[2];
    const float* bq = (const float*)d_in[3];
    const float* Wk = (const float*)d_in[4];
    const float* bk = (const float*)d_in[5];
    const float* Wv = (const float*)d_in[6];
    const float* bv = (const float*)d_in[7];
    const float* Wf = (const float*)d_in[8];
    const float* bf = (const float*)d_in[9];
    const int* st = (const int*)d_in[10];
    const int* en = (const int*)d_in[11];
    (void)in_sizes; (void)n_in; (void)out_size; (void)ws_size;

    char* ws = (char*)d_ws;
    unsigned short* KV2 = (unsigned short*)ws;                      // 128 MB
    float* Qb    = (float*)(ws + 134217728);                        // 4 MB
    float* attnb = (float*)(ws + 134217728 + 4194304);              // 4 MB
    float* outf  = (float*)d_out;

    kv_gemm_rb<<<dim3(1024), dim3(512), 0, stream>>>(social, Wk, bk, Wv, bv, KV2);
    gemm_proj<1><<<dim3(64, 4), dim3(256), 0, stream>>>(enc, Wq, bq, Qb, 0.0625f);
    attn_kernel<<<dim3(16384), dim3(64), 0, stream>>>(Qb, KV2, st, en, attnb);
    gemm_proj<0><<<dim3(64, 4), dim3(256), 0, stream>>>(attnb, Wf, bf, outf, 1.0f);
}